// Round 1
// baseline (15324.974 us; speedup 1.0000x reference)
//
#include <hip/hip_runtime.h>

#define TT 365
#define BBATCH 512
#define DD 16
#define HH 256
#define SS 32

typedef __attribute__((ext_vector_type(8))) short short8;
typedef __attribute__((ext_vector_type(4))) float f32x4;

__device__ __host__ inline short f2bf(float f){
  union { float f; unsigned u; } v; v.f = f;
  unsigned r = v.u + 0x7FFFu + ((v.u >> 16) & 1u);
  return (short)(r >> 16);
}
__device__ inline float sigm(float x){ return 1.0f/(1.0f+__expf(-x)); }
__device__ inline float tanhx(float x){ return 2.0f/(1.0f+__expf(-2.0f*x)) - 1.0f; }

// ---------------- prep kernels ----------------

// Swizzle weights into per-wave MFMA B-fragment streams (bf16).
// Layer0: K=288 (k<16: Wih0, 16<=k<272: Whh0, pad 0) -> 9 ksteps
// Layer1: K=512 (k<256: Wih1, else Whh1)             -> 16 ksteps
// frag id layout: [w][ks][nt], element: [lane][jj]
__global__ void prep_weights(const float* __restrict__ Wih0, const float* __restrict__ Whh0,
                             const float* __restrict__ Wih1, const float* __restrict__ Whh1,
                             short* __restrict__ Wbuf0, short* __restrict__ Wbuf1)
{
  int idx = blockIdx.x*blockDim.x + threadIdx.x;
  const int n0 = 16*36*512;  // 294912
  const int n1 = 16*64*512;  // 524288
  if (idx < n0){
    int frag = idx >> 9, pos = idx & 511;
    int lane = pos >> 3, jj = pos & 7;
    int w = frag / 36, rem = frag % 36;
    int ks = rem >> 2, nt = rem & 3;
    int n = 16*w + 256*nt + (lane & 15);
    int k = ks*32 + (lane>>4)*8 + jj;
    float v = 0.0f;
    if (k < 16)       v = Wih0[n*16 + k];
    else if (k < 272) v = Whh0[n*256 + (k-16)];
    Wbuf0[idx] = f2bf(v);
  } else if (idx < n0 + n1){
    int e = idx - n0;
    int frag = e >> 9, pos = e & 511;
    int lane = pos >> 3, jj = pos & 7;
    int w = frag >> 6, rem = frag & 63;
    int ks = rem >> 2, nt = rem & 3;
    int n = 16*w + 256*nt + (lane & 15);
    int k = ks*32 + (lane>>4)*8 + jj;
    float v = (k < 256) ? Wih1[n*256 + k] : Whh1[n*256 + (k-256)];
    Wbuf1[e] = f2bf(v);
  }
}

// h0init[b][j] = x_static[b] . Ws[j] + bs[j]   (f32, shared h0=c0 for both layers)
__global__ void prep_h0(const float* __restrict__ xs, const float* __restrict__ Ws,
                        const float* __restrict__ bs, float* __restrict__ h0init)
{
  int i = blockIdx.x*blockDim.x + threadIdx.x; // 131072
  int b = i >> 8, jj = i & 255;
  float s = bs[jj];
  const float* xr = xs + b*SS;
  const float* wr = Ws + jj*SS;
#pragma unroll
  for (int q=0;q<SS;++q) s += xr[q]*wr[q];
  h0init[i] = s;
}

__global__ void prep_bias(const float* __restrict__ a0, const float* __restrict__ a1,
                          const float* __restrict__ a2, const float* __restrict__ a3,
                          float* __restrict__ b0o, float* __restrict__ b1o)
{
  int i = threadIdx.x + blockIdx.x*blockDim.x;
  if (i < 1024) b0o[i] = a0[i] + a1[i];
  else if (i < 2048) b1o[i-1024] = a2[i-1024] + a3[i-1024];
}

__global__ void prep_x(const float* __restrict__ x, short* __restrict__ xbf, int n)
{
  int i = blockIdx.x*blockDim.x + threadIdx.x;
  if (i < n) xbf[i] = f2bf(x[i]);
}

// ---------------- persistent LSTM kernel ----------------
// 32 blocks x 1024 threads. Block = 16 batch rows, all 365 steps, both layers.
// Wave w owns hidden slice j in [16w, 16w+16): gate n-tiles {16w, 16w+256, 16w+512, 16w+768}.
// Weights register-resident (400 VGPR/lane). A-operands staged in LDS in MFMA
// fragment order: element (k,m) at short index (k>>5)*512 + (((k&31)>>3)*16+m)*8 + (k&7),
// so lane's ds_read_b128 at ks*512 + lane*8 is conflict-free.
__global__ __launch_bounds__(1024) void lstm_persistent(
    const short* __restrict__ Wbuf0, const short* __restrict__ Wbuf1,
    const float* __restrict__ h0init, const float* __restrict__ bias0g,
    const float* __restrict__ bias1g, const short* __restrict__ xbf,
    const float* __restrict__ Wo, const float* __restrict__ bo,
    float* __restrict__ out)
{
  __shared__ alignas(16) short A0[9*512];    // [x_t(16) | h0_prev(256) | pad(16)] K=288
  __shared__ alignas(16) short A1[16*512];   // [h0_t(256) | h1_prev(256)] K=512
  __shared__ float outacc[16][16];           // [b][w]

  const int tid  = threadIdx.x;
  const int w    = tid >> 6;
  const int lane = tid & 63;
  const int col  = lane & 15;
  const int quad = lane >> 4;
  const int rowbase = blockIdx.x * 16;
  const int j = 16*w + col;                  // hidden index this lane owns

  // ---- load register-resident B fragment streams ----
  short8 F0[36], F1[64];
  {
    const short8* p0 = (const short8*)Wbuf0 + (w*36)*64 + lane;
#pragma unroll
    for (int f=0; f<36; ++f) F0[f] = p0[f*64];
    const short8* p1 = (const short8*)Wbuf1 + (w*64)*64 + lane;
#pragma unroll
    for (int f=0; f<64; ++f) F1[f] = p1[f*64];
  }
  float bia0[4], bia1[4];
#pragma unroll
  for (int nt=0; nt<4; ++nt){
    bia0[nt] = bias0g[16*w + 256*nt + col];
    bia1[nt] = bias1g[16*w + 256*nt + col];
  }
  const float wo  = Wo[j];
  const float bos = bo[0];

  // ---- init states: h0 = c0 = static projection (both layers) ----
  float c0[4], c1[4];
#pragma unroll
  for (int r=0; r<4; ++r){
    int b = quad*4 + r;
    float hv = h0init[(rowbase+b)*HH + j];
    c0[r] = hv; c1[r] = hv;
    short hb = f2bf(hv);
    { int k = 16 + j;  A0[(k>>5)*512 + (((k&31)>>3)*16 + b)*8 + (k&7)] = hb; }
    { int k = 256 + j; A1[(k>>5)*512 + (((k&31)>>3)*16 + b)*8 + (k&7)] = hb; }
  }
  if (tid < 256) A0[8*512 + 256 + tid] = 0;   // zero K-pad [272,288)
  __syncthreads();

  const f32x4 zero = {0.0f, 0.0f, 0.0f, 0.0f};

  for (int t=0; t<TT; ++t){
    // stage x_t into A0 kstep 0 (k<16)
    if (tid < 256){
      int b = tid >> 4, d = tid & 15;
      short xv = xbf[(rowbase+b)*(TT*DD) + t*DD + d];
      A0[((d>>3)*16 + b)*8 + (d&7)] = xv;
    }
    __syncthreads();   // S1: x staged; prev-step h1 writes visible

    // ---- layer 0: gates = [x_t | h0_prev] @ Wcat0^T ----
    f32x4 acc[4];
#pragma unroll
    for (int nt=0; nt<4; ++nt) acc[nt] = zero;
#pragma unroll
    for (int ks=0; ks<9; ++ks){
      short8 a = *(const short8*)(A0 + ks*512 + lane*8);
#pragma unroll
      for (int nt=0; nt<4; ++nt)
        acc[nt] = __builtin_amdgcn_mfma_f32_16x16x32_bf16(a, F0[ks*4+nt], acc[nt], 0,0,0);
    }
    float h0v[4];
#pragma unroll
    for (int r=0; r<4; ++r){
      float iv = sigm (acc[0][r] + bia0[0]);
      float fv = sigm (acc[1][r] + bia0[1]);
      float gv = tanhx(acc[2][r] + bia0[2]);
      float ov = sigm (acc[3][r] + bia0[3]);
      float c = fv*c0[r] + iv*gv;
      c0[r] = c;
      h0v[r] = ov * tanhx(c);
    }
    __syncthreads();   // S2: all waves done reading A0/A1 h-regions

    // write h0_t into A0 (next step's recurrence) and A1 (layer1 input)
#pragma unroll
    for (int r=0; r<4; ++r){
      int b = quad*4 + r; short hb = f2bf(h0v[r]);
      { int k = 16 + j; A0[(k>>5)*512 + (((k&31)>>3)*16 + b)*8 + (k&7)] = hb; }
      { int k = j;      A1[(k>>5)*512 + (((k&31)>>3)*16 + b)*8 + (k&7)] = hb; }
    }
    __syncthreads();   // S3: h0_t visible

    // ---- layer 1: gates = [h0_t | h1_prev] @ Wcat1^T ----
#pragma unroll
    for (int nt=0; nt<4; ++nt) acc[nt] = zero;
#pragma unroll
    for (int ks=0; ks<16; ++ks){
      short8 a = *(const short8*)(A1 + ks*512 + lane*8);
#pragma unroll
      for (int nt=0; nt<4; ++nt)
        acc[nt] = __builtin_amdgcn_mfma_f32_16x16x32_bf16(a, F1[ks*4+nt], acc[nt], 0,0,0);
    }
    float h1v[4], pr[4];
#pragma unroll
    for (int r=0; r<4; ++r){
      float iv = sigm (acc[0][r] + bia1[0]);
      float fv = sigm (acc[1][r] + bia1[1]);
      float gv = tanhx(acc[2][r] + bia1[2]);
      float ov = sigm (acc[3][r] + bia1[3]);
      float c = fv*c1[r] + iv*gv;
      c1[r] = c;
      float h = ov * tanhx(c);
      h1v[r] = h;
      pr[r] = h * wo;      // out partial: h1[b][j] * Wo[j]
    }
    // reduce over the 16 j-columns of this wave (col dimension = lane&15)
#pragma unroll
    for (int m=1; m<16; m<<=1){
#pragma unroll
      for (int r=0; r<4; ++r) pr[r] += __shfl_xor(pr[r], m, 64);
    }
    if (col == 0){
#pragma unroll
      for (int r=0; r<4; ++r) outacc[quad*4 + r][w] = pr[r];
    }
    __syncthreads();   // S4: layer1 reads done; outacc complete

    // write h1_t for next step
#pragma unroll
    for (int r=0; r<4; ++r){
      int b = quad*4 + r; short hb = f2bf(h1v[r]);
      int k = 256 + j;
      A1[(k>>5)*512 + (((k&31)>>3)*16 + b)*8 + (k&7)] = hb;
    }
    // final out reduction across waves
    if (tid < 16){
      float s = bos;
#pragma unroll
      for (int wi=0; wi<16; ++wi) s += outacc[tid][wi];
      out[(rowbase+tid)*TT + t] = s;
    }
  }
}

// ---------------- launch ----------------
extern "C" void kernel_launch(void* const* d_in, const int* in_sizes, int n_in,
                              void* d_out, int out_size, void* d_ws, size_t ws_size,
                              hipStream_t stream)
{
  const float* x    = (const float*)d_in[0];
  const float* xs   = (const float*)d_in[1];
  const float* Wih0 = (const float*)d_in[2];
  const float* Whh0 = (const float*)d_in[3];
  const float* bih0 = (const float*)d_in[4];
  const float* bhh0 = (const float*)d_in[5];
  const float* Wih1 = (const float*)d_in[6];
  const float* Whh1 = (const float*)d_in[7];
  const float* bih1 = (const float*)d_in[8];
  const float* bhh1 = (const float*)d_in[9];
  const float* Ws   = (const float*)d_in[10];
  const float* bs   = (const float*)d_in[11];
  const float* Wo   = (const float*)d_in[12];
  const float* bo   = (const float*)d_in[13];
  float* out = (float*)d_out;

  char* ws = (char*)d_ws;
  short* Wbuf0 = (short*)(ws);              // 589824 B
  short* Wbuf1 = (short*)(ws + 589824);     // 1048576 B
  float* h0i   = (float*)(ws + 1638400);    // 524288 B
  float* b0c   = (float*)(ws + 2162688);    // 4096 B
  float* b1c   = (float*)(ws + 2166784);    // 4096 B
  short* xbf   = (short*)(ws + 2170880);    // 5980160 B  (total ~8.15 MB)

  int nswz = 16*36*512 + 16*64*512;
  hipLaunchKernelGGL(prep_weights, dim3((nswz+255)/256), dim3(256), 0, stream,
                     Wih0, Whh0, Wih1, Whh1, Wbuf0, Wbuf1);
  hipLaunchKernelGGL(prep_h0, dim3(512), dim3(256), 0, stream, xs, Ws, bs, h0i);
  hipLaunchKernelGGL(prep_bias, dim3(8), dim3(256), 0, stream, bih0, bhh0, bih1, bhh1, b0c, b1c);
  int nx = BBATCH*TT*DD;
  hipLaunchKernelGGL(prep_x, dim3((nx+255)/256), dim3(256), 0, stream, x, xbf, nx);

  hipLaunchKernelGGL(lstm_persistent, dim3(32), dim3(1024), 0, stream,
                     Wbuf0, Wbuf1, h0i, b0c, b1c, xbf, Wo, bo, out);
}

// Round 2
// 11941.486 us; speedup vs baseline: 1.2833x; 1.2833x over previous
//
#include <hip/hip_runtime.h>

#define TT 365
#define BB 512
#define DD 16
#define HH 256
#define SS 32

typedef __attribute__((ext_vector_type(8))) short short8;
typedef __attribute__((ext_vector_type(4))) short s16x4;
typedef __attribute__((ext_vector_type(4))) float f32x4;

__device__ __host__ inline short f2bf(float f){
  union { float f; unsigned u; } v; v.f = f;
  unsigned r = v.u + 0x7FFFu + ((v.u >> 16) & 1u);
  return (short)(r >> 16);
}
__device__ inline float sigm(float x){ return 1.0f/(1.0f+__expf(-x)); }
__device__ inline float tanhx(float x){ return 2.0f/(1.0f+__expf(-2.0f*x)) - 1.0f; }

// A-fragment address (shorts) within an 8KB K=256 region, for mfma_16x16x32 A-layout:
// element (k,m) -> (k>>5)*512 + (((k&31)>>3)*16 + m)*8 + (k&7); lane reads at lane*8.
__device__ inline int fragAddr(int k, int m){
  return ((k>>5)*512) + ((((k&31)>>3)*16 + m)*8) + (k&7);
}

// ---------------- prep kernels ----------------
// Per-(cu-role c, wave w) weight fragment streams. slot = c*4+w in [0,16).
// Wave's 4 n-tiles: n = nt*256 + slot*16 + (lane&15)  (gate nt of its 16 hidden cols).
// Wb0: [slot][ks=0..8][nt][lane][jj]; ks0: k32=(lane>>4)*8+jj: k32<16 -> Wih0, else 0.
//      ks 1..8: k=(ks-1)*32+(lane>>4)*8+jj -> Whh0[n][k].
// Wb1: [slot][ks=0..15][nt][lane][jj]; k=ks*32+...: k<256 -> Wih1[n][k] else Whh1[n][k-256].
__global__ void prep_weights(const float* __restrict__ Wih0, const float* __restrict__ Whh0,
                             const float* __restrict__ Wih1, const float* __restrict__ Whh1,
                             short* __restrict__ Wb0, short* __restrict__ Wb1)
{
  int idx = blockIdx.x*blockDim.x + threadIdx.x;
  const int n0 = 16*36*512;  // 294912
  const int n1 = 16*64*512;  // 524288
  if (idx < n0){
    int frag = idx >> 9, pos = idx & 511;
    int lane = pos >> 3, jj = pos & 7;
    int slot = frag / 36, rem = frag % 36;
    int ks = rem >> 2, nt = rem & 3;
    int n = nt*256 + slot*16 + (lane & 15);
    float v = 0.0f;
    if (ks == 0){
      int k32 = (lane>>4)*8 + jj;
      if (k32 < 16) v = Wih0[n*16 + k32];
    } else {
      int k = (ks-1)*32 + (lane>>4)*8 + jj;
      v = Whh0[n*256 + k];
    }
    Wb0[idx] = f2bf(v);
  } else if (idx < n0 + n1){
    int e = idx - n0;
    int frag = e >> 9, pos = e & 511;
    int lane = pos >> 3, jj = pos & 7;
    int slot = frag >> 6, rem = frag & 63;
    int ks = rem >> 2, nt = rem & 3;
    int n = nt*256 + slot*16 + (lane & 15);
    int k = ks*32 + (lane>>4)*8 + jj;
    float v = (k < 256) ? Wih1[n*256 + k] : Whh1[n*256 + (k-256)];
    Wb1[e] = f2bf(v);
  }
}

__global__ void prep_h0(const float* __restrict__ xs, const float* __restrict__ Ws,
                        const float* __restrict__ bs, float* __restrict__ h0init)
{
  int i = blockIdx.x*blockDim.x + threadIdx.x; // 131072
  int b = i >> 8, jj = i & 255;
  float s = bs[jj];
  const float* xr = xs + b*SS;
  const float* wr = Ws + jj*SS;
#pragma unroll
  for (int q=0;q<SS;++q) s += xr[q]*wr[q];
  h0init[i] = s;
}

__global__ void prep_bias(const float* __restrict__ a0, const float* __restrict__ a1,
                          const float* __restrict__ a2, const float* __restrict__ a3,
                          float* __restrict__ b0o, float* __restrict__ b1o)
{
  int i = threadIdx.x + blockIdx.x*blockDim.x;
  if (i < 1024) b0o[i] = a0[i] + a1[i];
  else if (i < 2048) b1o[i-1024] = a2[i-1024] + a3[i-1024];
}

__global__ void prep_x(const float* __restrict__ x, short* __restrict__ xbf, int n)
{
  int i = blockIdx.x*blockDim.x + threadIdx.x;
  if (i < n) xbf[i] = f2bf(x[i]);
}

// zero out[] (atomicAdd target) and flags[]
__global__ void prep_zero(float* __restrict__ out, unsigned* __restrict__ flags)
{
  int i = blockIdx.x*blockDim.x + threadIdx.x;
  if (i < BB*TT) out[i] = 0.0f;
  if (i < 128) flags[i] = 0u;
}

// ---------------- persistent fused LSTM ----------------
// 128 blocks x 256 threads. group g = blockIdx&31 (16 batch rows), role c = blockIdx>>5
// (64 hidden cols: cols [c*64, c*64+64)). 4 waves/block; wave w owns 16 cols
// (slot = c*4+w), all 4 gates (4 n-tiles), both layers. Weights register/AGPR-resident:
// F0[36] + F1[64] short8 = 400 regs/lane. Superstep s: layer0@t=s, layer1@t=s-1,
// then ONE 4-way h-exchange through global ring + device-scope flags.
__global__ __launch_bounds__(256, 1) void lstm_fused(
    const short* __restrict__ Wb0, const short* __restrict__ Wb1,
    const float* __restrict__ h0i, const float* __restrict__ b0c,
    const float* __restrict__ b1c, const short* __restrict__ xbf,
    const float* __restrict__ Wo, const float* __restrict__ bo,
    short* __restrict__ h0r, short* __restrict__ h1r,
    unsigned* __restrict__ flags, float* __restrict__ out)
{
  __shared__ alignas(16) short AX[512];     // x_t frags, K=32 (k>=16 zero)
  __shared__ alignas(16) short AH0[4096];   // h0_prev frags, K=256
  __shared__ alignas(16) short AH1[4096];   // h1_prev frags, K=256
  __shared__ float outacc[16][4];

  const int tid  = threadIdx.x;
  const int w    = tid >> 6;
  const int lane = tid & 63;
  const int col16= lane & 15;
  const int quad = lane >> 4;
  const int c    = blockIdx.x >> 5;
  const int g    = blockIdx.x & 31;
  const int rowbase = g * 16;
  const int slot = c*4 + w;
  const int colg = slot*16 + col16;   // global hidden col this lane owns

  // ---- register-resident weight fragments ----
  short8 F0[36], F1[64];
  {
    const short8* p0 = (const short8*)Wb0 + slot*36*64 + lane;
#pragma unroll
    for (int f=0; f<36; ++f) F0[f] = p0[f*64];
    const short8* p1 = (const short8*)Wb1 + slot*64*64 + lane;
#pragma unroll
    for (int f=0; f<64; ++f) F1[f] = p1[f*64];
  }
  float bia0[4], bia1[4];
#pragma unroll
  for (int nt=0; nt<4; ++nt){
    bia0[nt] = b0c[nt*256 + slot*16 + col16];
    bia1[nt] = b1c[nt*256 + slot*16 + col16];
  }
  const float wo  = Wo[colg];
  const float bos = bo[0];

  // ---- init: c0=c1=h0init; stage full AH0/AH1 with h0init; stage x_0; zero AX pad ----
  float c0[4], c1[4];
#pragma unroll
  for (int r=0; r<4; ++r){
    c0[r] = h0i[(rowbase + quad*4 + r)*HH + colg];
    c1[r] = c0[r];
  }
  for (int i = tid; i < 4096; i += 256){
    int m = i >> 8, k = i & 255;
    short v = f2bf(h0i[(rowbase+m)*HH + k]);
    AH0[fragAddr(k,m)] = v;
    AH1[fragAddr(k,m)] = v;
  }
  {
    int m = tid >> 4, d = tid & 15;
    AX[fragAddr(d, m)]      = xbf[((rowbase+m)*TT + 0)*DD + d];
    AX[fragAddr(16 + d, m)] = 0;   // K-pad [16,32)
  }
  __syncthreads();

  const f32x4 zero = {0.0f,0.0f,0.0f,0.0f};
  unsigned* const myflag = flags + g*4 + c;

  for (int s=0; s<=TT; ++s){
    const bool doL0 = (s < TT);
    const bool doL1 = (s >= 1);

    // ---- MFMA phase ----
    f32x4 acc0[4], acc1[4];
#pragma unroll
    for (int nt=0; nt<4; ++nt){ acc0[nt]=zero; acc1[nt]=zero; }
    if (doL0){
      short8 a = *(const short8*)(AX + lane*8);
#pragma unroll
      for (int nt=0; nt<4; ++nt)
        acc0[nt] = __builtin_amdgcn_mfma_f32_16x16x32_bf16(a, F0[nt], acc0[nt], 0,0,0);
    }
#pragma unroll
    for (int ks=0; ks<8; ++ks){
      short8 a = *(const short8*)(AH0 + ks*512 + lane*8);
      if (doL0){
#pragma unroll
        for (int nt=0; nt<4; ++nt)
          acc0[nt] = __builtin_amdgcn_mfma_f32_16x16x32_bf16(a, F0[(ks+1)*4+nt], acc0[nt], 0,0,0);
      }
      if (doL1){
#pragma unroll
        for (int nt=0; nt<4; ++nt)
          acc1[nt] = __builtin_amdgcn_mfma_f32_16x16x32_bf16(a, F1[ks*4+nt], acc1[nt], 0,0,0);
      }
    }
    if (doL1){
#pragma unroll
      for (int ks=0; ks<8; ++ks){
        short8 a = *(const short8*)(AH1 + ks*512 + lane*8);
#pragma unroll
        for (int nt=0; nt<4; ++nt)
          acc1[nt] = __builtin_amdgcn_mfma_f32_16x16x32_bf16(a, F1[32+ks*4+nt], acc1[nt], 0,0,0);
      }
    }

    // ---- epilogues (registers only) ----
    float h0v[4], h1v[4], pr[4];
    if (doL0){
#pragma unroll
      for (int r=0; r<4; ++r){
        float iv = sigm (acc0[0][r] + bia0[0]);
        float fv = sigm (acc0[1][r] + bia0[1]);
        float gv = tanhx(acc0[2][r] + bia0[2]);
        float ov = sigm (acc0[3][r] + bia0[3]);
        float cc = fv*c0[r] + iv*gv;
        c0[r] = cc;
        h0v[r] = ov * tanhx(cc);
      }
    }
    if (doL1){
#pragma unroll
      for (int r=0; r<4; ++r){
        float iv = sigm (acc1[0][r] + bia1[0]);
        float fv = sigm (acc1[1][r] + bia1[1]);
        float gv = tanhx(acc1[2][r] + bia1[2]);
        float ov = sigm (acc1[3][r] + bia1[3]);
        float cc = fv*c1[r] + iv*gv;
        c1[r] = cc;
        float h = ov * tanhx(cc);
        h1v[r] = h;
        pr[r] = h * wo;
      }
      // reduce out partial over this wave's 16 cols
#pragma unroll
      for (int m=1; m<16; m<<=1){
#pragma unroll
        for (int r=0; r<4; ++r) pr[r] += __shfl_xor(pr[r], m, 64);
      }
      if (col16 == 0){
#pragma unroll
        for (int r=0; r<4; ++r) outacc[quad*4 + r][w] = pr[r];
      }
    }

    // ---- publish own slices to global ring ----
    if (doL0){
      int slt = s & 3;
#pragma unroll
      for (int r=0; r<4; ++r)
        h0r[(slt*BB + rowbase + quad*4 + r)*HH + colg] = f2bf(h0v[r]);
    }
    if (doL1){
      int slt = (s-1) & 3;
#pragma unroll
      for (int r=0; r<4; ++r)
        h1r[(slt*BB + rowbase + quad*4 + r)*HH + colg] = f2bf(h1v[r]);
    }
    __threadfence();
    __syncthreads();   // B1: all global writes issued+fenced, all LDS reads done

    if (s < TT && tid == 0)
      __hip_atomic_store(myflag, (unsigned)(s+1), __ATOMIC_RELEASE, __HIP_MEMORY_SCOPE_AGENT);

    // own h values into LDS fragments for next superstep
    if (doL0){
#pragma unroll
      for (int r=0; r<4; ++r)
        AH0[fragAddr(colg, quad*4 + r)] = f2bf(h0v[r]);
    }
    if (doL1 && s < TT){
#pragma unroll
      for (int r=0; r<4; ++r)
        AH1[fragAddr(colg, quad*4 + r)] = f2bf(h1v[r]);
    }
    // stage x_{s+1}
    if (s+1 < TT){
      int m = tid >> 4, d = tid & 15;
      AX[fragAddr(d, m)] = xbf[((rowbase+m)*TT + (s+1))*DD + d];
    }
    // final out reduction for t=s-1
    if (doL1 && tid < 16){
      float v = outacc[tid][0] + outacc[tid][1] + outacc[tid][2] + outacc[tid][3];
      if (c == 0) v += bos;
      atomicAdd(&out[(rowbase + tid)*TT + (s-1)], v);
    }

    // ---- wait partners, stage their slices ----
    if (s < TT){
      unsigned target = (unsigned)(s+1);
#pragma unroll
      for (int p=0; p<4; ++p){
        if (p == c) continue;
        const unsigned* fp = flags + g*4 + p;
        while (__hip_atomic_load(fp, __ATOMIC_ACQUIRE, __HIP_MEMORY_SCOPE_AGENT) < target) {}
      }
      // cooperative read of 3 partner slices (16 rows x 64 cols each)
      int r4 = tid >> 4, c4 = (tid & 15) * 4;
      int slt0 = s & 3;
#pragma unroll
      for (int p=0; p<4; ++p){
        if (p == c) continue;
        int k0 = p*64 + c4;
        s16x4 v = *(const s16x4*)(h0r + (slt0*BB + rowbase + r4)*HH + k0);
        *(s16x4*)(AH0 + fragAddr(k0, r4)) = v;
      }
      if (s >= 1){
        int slt1 = (s-1) & 3;
#pragma unroll
        for (int p=0; p<4; ++p){
          if (p == c) continue;
          int k0 = p*64 + c4;
          s16x4 v = *(const s16x4*)(h1r + (slt1*BB + rowbase + r4)*HH + k0);
          *(s16x4*)(AH1 + fragAddr(k0, r4)) = v;
        }
      }
    }
    __syncthreads();   // B2: LDS staged for next superstep
  }
}

// ---------------- launch ----------------
extern "C" void kernel_launch(void* const* d_in, const int* in_sizes, int n_in,
                              void* d_out, int out_size, void* d_ws, size_t ws_size,
                              hipStream_t stream)
{
  const float* x    = (const float*)d_in[0];
  const float* xs   = (const float*)d_in[1];
  const float* Wih0 = (const float*)d_in[2];
  const float* Whh0 = (const float*)d_in[3];
  const float* bih0 = (const float*)d_in[4];
  const float* bhh0 = (const float*)d_in[5];
  const float* Wih1 = (const float*)d_in[6];
  const float* Whh1 = (const float*)d_in[7];
  const float* bih1 = (const float*)d_in[8];
  const float* bhh1 = (const float*)d_in[9];
  const float* Ws   = (const float*)d_in[10];
  const float* bs   = (const float*)d_in[11];
  const float* Wo   = (const float*)d_in[12];
  const float* bo   = (const float*)d_in[13];
  float* out = (float*)d_out;

  char* ws = (char*)d_ws;
  short*    Wb0   = (short*)(ws);                 // 589824 B
  short*    Wb1   = (short*)(ws + 589824);        // 1048576 B -> 1638400
  float*    h0i   = (float*)(ws + 1638400);       // 524288 B  -> 2162688
  float*    b0cp  = (float*)(ws + 2162688);       // 4096 B    -> 2166784
  float*    b1cp  = (float*)(ws + 2166784);       // 4096 B    -> 2170880
  short*    xbf   = (short*)(ws + 2170880);       // 5980160 B -> 8151040
  short*    h0r   = (short*)(ws + 8151040);       // 1048576 B -> 9199616
  short*    h1r   = (short*)(ws + 9199616);       // 1048576 B -> 10248192
  unsigned* flags = (unsigned*)(ws + 10248192);   // 512 B     (~10.25 MB total)

  int nswz = 16*36*512 + 16*64*512;
  hipLaunchKernelGGL(prep_weights, dim3((nswz+255)/256), dim3(256), 0, stream,
                     Wih0, Whh0, Wih1, Whh1, Wb0, Wb1);
  hipLaunchKernelGGL(prep_h0, dim3(512), dim3(256), 0, stream, xs, Ws, bs, h0i);
  hipLaunchKernelGGL(prep_bias, dim3(8), dim3(256), 0, stream, bih0, bhh0, bih1, bhh1, b0cp, b1cp);
  int nx = BB*TT*DD;
  hipLaunchKernelGGL(prep_x, dim3((nx+255)/256), dim3(256), 0, stream, x, xbf, nx);
  hipLaunchKernelGGL(prep_zero, dim3((BB*TT+255)/256), dim3(256), 0, stream, out, flags);

  hipLaunchKernelGGL(lstm_fused, dim3(128), dim3(256), 0, stream,
                     Wb0, Wb1, h0i, b0cp, b1cp, xbf, Wo, bo, h0r, h1r, flags, out);
}

// Round 4
// 3023.321 us; speedup vs baseline: 5.0689x; 3.9498x over previous
//
#include <hip/hip_runtime.h>

#define TT 365
#define BB 512
#define DD 16
#define HH 256
#define SS 32

typedef __attribute__((ext_vector_type(8))) short short8;
typedef __attribute__((ext_vector_type(4))) float f32x4;
typedef unsigned long long u64;

__device__ __host__ inline short f2bf(float f){
  union { float f; unsigned u; } v; v.f = f;
  unsigned r = v.u + 0x7FFFu + ((v.u >> 16) & 1u);
  return (short)(r >> 16);
}
__device__ inline float sigm(float x){ return 1.0f/(1.0f+__expf(-x)); }
__device__ inline float tanhx(float x){ return 2.0f/(1.0f+__expf(-2.0f*x)) - 1.0f; }

// A-fragment address (shorts) in an 8KB K=256 region for mfma_16x16x32 A-layout.
__device__ inline int fragAddr(int k, int m){
  return ((k>>5)*512) + ((((k&31)>>3)*16 + m)*8) + (k&7);
}

// ---------------- prep kernels ----------------
__global__ void prep_weights(const float* __restrict__ Wih0, const float* __restrict__ Whh0,
                             const float* __restrict__ Wih1, const float* __restrict__ Whh1,
                             short* __restrict__ Wb0, short* __restrict__ Wb1)
{
  int idx = blockIdx.x*blockDim.x + threadIdx.x;
  const int n0 = 16*36*512;
  const int n1 = 16*64*512;
  if (idx < n0){
    int frag = idx >> 9, pos = idx & 511;
    int lane = pos >> 3, jj = pos & 7;
    int slot = frag / 36, rem = frag % 36;
    int ks = rem >> 2, nt = rem & 3;
    int n = nt*256 + slot*16 + (lane & 15);
    float v = 0.0f;
    if (ks == 0){
      int k32 = (lane>>4)*8 + jj;
      if (k32 < 16) v = Wih0[n*16 + k32];
    } else {
      int k = (ks-1)*32 + (lane>>4)*8 + jj;
      v = Whh0[n*256 + k];
    }
    Wb0[idx] = f2bf(v);
  } else if (idx < n0 + n1){
    int e = idx - n0;
    int frag = e >> 9, pos = e & 511;
    int lane = pos >> 3, jj = pos & 7;
    int slot = frag >> 6, rem = frag & 63;
    int ks = rem >> 2, nt = rem & 3;
    int n = nt*256 + slot*16 + (lane & 15);
    int k = ks*32 + (lane>>4)*8 + jj;
    float v = (k < 256) ? Wih1[n*256 + k] : Whh1[n*256 + (k-256)];
    Wb1[e] = f2bf(v);
  }
}

__global__ void prep_h0(const float* __restrict__ xs, const float* __restrict__ Ws,
                        const float* __restrict__ bs, float* __restrict__ h0init)
{
  int i = blockIdx.x*blockDim.x + threadIdx.x;
  int b = i >> 8, jj = i & 255;
  float s = bs[jj];
  const float* xr = xs + b*SS;
  const float* wr = Ws + jj*SS;
#pragma unroll
  for (int q=0;q<SS;++q) s += xr[q]*wr[q];
  h0init[i] = s;
}

__global__ void prep_bias(const float* __restrict__ a0, const float* __restrict__ a1,
                          const float* __restrict__ a2, const float* __restrict__ a3,
                          float* __restrict__ b0o, float* __restrict__ b1o)
{
  int i = threadIdx.x + blockIdx.x*blockDim.x;
  if (i < 1024) b0o[i] = a0[i] + a1[i];
  else if (i < 2048) b1o[i-1024] = a2[i-1024] + a3[i-1024];
}

// zero out (atomicAdd target) + flags
__global__ void prep_zero(float* __restrict__ out, unsigned* __restrict__ flags)
{
  int i = blockIdx.x*blockDim.x + threadIdx.x;
  if (i < BB*TT) out[i] = 0.0f;
  if (i < 4096) flags[i] = 0u;
}

// ---------------- persistent fused LSTM ----------------
// 128 blocks x 256 threads; g = bid&31 (16 batch rows), c = bid>>5 (64 hidden cols).
// Weights register/AGPR-resident (F0[36]+F1[64] short8 = 400 regs/lane).
// Lag pipeline: superstep s runs L0@t=s and L1@t=s-1; ONE 4-way exchange/step.
// Publish = atomicExch RMW (executes at coherence point, result consumed so it
// can't be downgraded); poll = 3 lanes, relaxed spin with acquire-load exit
// (buffer_inv) => plain vector loads after the barrier read fresh data.
__global__ __launch_bounds__(256, 1) void lstm_fused(
    const short* __restrict__ Wb0, const short* __restrict__ Wb1,
    const float* __restrict__ h0i, const float* __restrict__ b0c,
    const float* __restrict__ b1c, const float* __restrict__ x,
    const float* __restrict__ Wo, const float* __restrict__ bo,
    short* __restrict__ ring0, short* __restrict__ ring1,
    unsigned* __restrict__ flags, unsigned* __restrict__ sinkbuf,
    float* __restrict__ out)
{
  __shared__ alignas(16) short AX[512];     // x_t frags, K=32 (k>=16 zero)
  __shared__ alignas(16) short AH0[4096];   // h0[t-1] frags, K=256
  __shared__ alignas(16) short AH1[4096];   // h1[t-2] frags, K=256
  __shared__ float outacc[16][4];
  __shared__ float outLDS[TT][16];          // per-block out partials (23.4 KB)

  const int tid  = threadIdx.x;
  const int w    = tid >> 6;
  const int lane = tid & 63;
  const int col16= lane & 15;
  const int quad = lane >> 4;
  const int c    = blockIdx.x >> 5;
  const int g    = blockIdx.x & 31;
  const int rowbase = g * 16;
  const int slot = c*4 + w;
  const int colg = slot*16 + col16;

  unsigned sink = 0;

  // ---- register-resident weight fragments ----
  short8 F0[36], F1[64];
  {
    const short8* p0 = (const short8*)Wb0 + slot*36*64 + lane;
#pragma unroll
    for (int f=0; f<36; ++f) F0[f] = p0[f*64];
    const short8* p1 = (const short8*)Wb1 + slot*64*64 + lane;
#pragma unroll
    for (int f=0; f<64; ++f) F1[f] = p1[f*64];
  }
  float bia0[4], bia1[4];
#pragma unroll
  for (int nt=0; nt<4; ++nt){
    bia0[nt] = b0c[nt*256 + slot*16 + col16];
    bia1[nt] = b1c[nt*256 + slot*16 + col16];
  }
  const float wo = Wo[colg];

  // ---- init ----
  float c0[4], c1[4];
#pragma unroll
  for (int r=0; r<4; ++r){
    c0[r] = h0i[(rowbase + quad*4 + r)*HH + colg];
    c1[r] = c0[r];
  }
  for (int i = tid; i < 4096; i += 256){
    int m = i >> 8, k = i & 255;
    short v = f2bf(h0i[(rowbase+m)*HH + k]);
    AH0[fragAddr(k,m)] = v;
    AH1[fragAddr(k,m)] = v;
  }
  {
    int m = tid >> 4, d = tid & 15;
    AX[fragAddr(d, m)]      = f2bf(x[(rowbase+m)*TT*DD + d]);
    AX[fragAddr(16 + d, m)] = 0;
  }
  __syncthreads();

  const f32x4 zero = {0.0f,0.0f,0.0f,0.0f};

  for (int s=0; s<=TT; ++s){
    const bool doL0 = (s < TT);
    const bool doL1 = (s >= 1);

    // prefetch x_{s+1} (hidden under MFMAs)
    float xf = 0.0f;
    if (s+1 < TT){
      int m = tid >> 4, d = tid & 15;
      xf = x[(rowbase+m)*TT*DD + (s+1)*DD + d];
    }

    // ---- MFMA phase ----
    f32x4 acc0[4], acc1[4];
#pragma unroll
    for (int nt=0; nt<4; ++nt){ acc0[nt]=zero; acc1[nt]=zero; }
    if (doL0){
      short8 a = *(const short8*)(AX + lane*8);
#pragma unroll
      for (int nt=0; nt<4; ++nt)
        acc0[nt] = __builtin_amdgcn_mfma_f32_16x16x32_bf16(a, F0[nt], acc0[nt], 0,0,0);
    }
#pragma unroll
    for (int ks=0; ks<8; ++ks){
      short8 a = *(const short8*)(AH0 + ks*512 + lane*8);
      if (doL0){
#pragma unroll
        for (int nt=0; nt<4; ++nt)
          acc0[nt] = __builtin_amdgcn_mfma_f32_16x16x32_bf16(a, F0[(ks+1)*4+nt], acc0[nt], 0,0,0);
      }
      if (doL1){
#pragma unroll
        for (int nt=0; nt<4; ++nt)
          acc1[nt] = __builtin_amdgcn_mfma_f32_16x16x32_bf16(a, F1[ks*4+nt], acc1[nt], 0,0,0);
      }
    }
    if (doL1){
#pragma unroll
      for (int ks=0; ks<8; ++ks){
        short8 a = *(const short8*)(AH1 + ks*512 + lane*8);
#pragma unroll
        for (int nt=0; nt<4; ++nt)
          acc1[nt] = __builtin_amdgcn_mfma_f32_16x16x32_bf16(a, F1[32+ks*4+nt], acc1[nt], 0,0,0);
      }
    }

    // ---- epilogues ----
    float h0v[4], h1v[4], pr[4];
    if (doL0){
#pragma unroll
      for (int r=0; r<4; ++r){
        float iv = sigm (acc0[0][r] + bia0[0]);
        float fv = sigm (acc0[1][r] + bia0[1]);
        float gv = tanhx(acc0[2][r] + bia0[2]);
        float ov = sigm (acc0[3][r] + bia0[3]);
        float cc = fv*c0[r] + iv*gv;
        c0[r] = cc;
        h0v[r] = ov * tanhx(cc);
      }
    }
    if (doL1){
#pragma unroll
      for (int r=0; r<4; ++r){
        float iv = sigm (acc1[0][r] + bia1[0]);
        float fv = sigm (acc1[1][r] + bia1[1]);
        float gv = tanhx(acc1[2][r] + bia1[2]);
        float ov = sigm (acc1[3][r] + bia1[3]);
        float cc = fv*c1[r] + iv*gv;
        c1[r] = cc;
        float h = ov * tanhx(cc);
        h1v[r] = h;
        pr[r] = h * wo;
      }
#pragma unroll
      for (int m=1; m<16; m<<=1){
#pragma unroll
        for (int r=0; r<4; ++r) pr[r] += __shfl_xor(pr[r], m, 64);
      }
      if (col16 == 0){
#pragma unroll
        for (int r=0; r<4; ++r) outacc[quad*4 + r][w] = pr[r];
      }
    }

    // ---- publish own slices: 8B atomicExch RMW (coherence-point write) ----
    if (doL0){
      int slt = s & 3;
      u64 pv; short* ps = (short*)&pv;
#pragma unroll
      for (int r=0; r<4; ++r) ps[r] = f2bf(h0v[r]);
      u64 old = __hip_atomic_exchange(
          (u64*)(ring0 + ((slt*32+g)*256 + colg)*16 + quad*4), pv,
          __ATOMIC_RELAXED, __HIP_MEMORY_SCOPE_AGENT);
      sink ^= (unsigned)old;
    }
    if (doL1){
      int slt = (s-1) & 3;
      u64 pv; short* ps = (short*)&pv;
#pragma unroll
      for (int r=0; r<4; ++r) ps[r] = f2bf(h1v[r]);
      u64 old = __hip_atomic_exchange(
          (u64*)(ring1 + ((slt*32+g)*256 + colg)*16 + quad*4), pv,
          __ATOMIC_RELAXED, __HIP_MEMORY_SCOPE_AGENT);
      sink ^= (unsigned)old;
    }
    __builtin_amdgcn_s_waitcnt(0x0F70);  // vmcnt(0): RMWs completed at coherence point
    __syncthreads();                     // B1

    if (s < TT && tid == 0){
      unsigned oldf = __hip_atomic_exchange(&flags[(g*4+c)*32], (unsigned)(s+1),
                                            __ATOMIC_RELAXED, __HIP_MEMORY_SCOPE_AGENT);
      sink ^= oldf;
    }

    // own h into LDS frags; stage x_{s+1}; out partial for t=s-1
    if (doL0){
#pragma unroll
      for (int r=0; r<4; ++r) AH0[fragAddr(colg, quad*4 + r)] = f2bf(h0v[r]);
    }
    if (doL1 && s < TT){
#pragma unroll
      for (int r=0; r<4; ++r) AH1[fragAddr(colg, quad*4 + r)] = f2bf(h1v[r]);
    }
    if (s+1 < TT){
      int m = tid >> 4, d = tid & 15;
      AX[fragAddr(d, m)] = f2bf(xf);
    }
    if (doL1 && tid < 16)
      outLDS[s-1][tid] = outacc[tid][0] + outacc[tid][1] + outacc[tid][2] + outacc[tid][3];

    // ---- wait partners (3 lanes), acquire on exit => inv before data reads ----
    if (s < TT){
      if (tid < 3){
        int p = (c + 1 + tid) & 3;
        const unsigned* fp = flags + (g*4+p)*32;
        unsigned target = (unsigned)(s+1);
        unsigned spin = 0;
        while (true){
          if (__hip_atomic_load(fp, __ATOMIC_RELAXED, __HIP_MEMORY_SCOPE_AGENT) >= target){
            (void)__hip_atomic_load(fp, __ATOMIC_ACQUIRE, __HIP_MEMORY_SCOPE_AGENT);
            break;
          }
          if (((++spin) & 63u) == 0u){
            if (__hip_atomic_load(fp, __ATOMIC_ACQUIRE, __HIP_MEMORY_SCOPE_AGENT) >= target)
              break;
          }
        }
      }
      __syncthreads();  // B2: flags observed + caches invalidated

      int qd = tid & 3;
      int cl = (tid >> 2) & 63;
      int slt0 = s & 3;
      int slt1 = (s-1) & 3;
#pragma unroll
      for (int pi=0; pi<3; ++pi){
        int p = (c + 1 + pi) & 3;
        int k = p*64 + cl;
        u64 v0 = *(const u64*)(ring0 + ((slt0*32+g)*256 + k)*16 + qd*4);
        short* sv = (short*)&v0;
#pragma unroll
        for (int r=0; r<4; ++r) AH0[fragAddr(k, qd*4 + r)] = sv[r];
        if (s >= 1){
          u64 v1 = *(const u64*)(ring1 + ((slt1*32+g)*256 + k)*16 + qd*4);
          short* sw = (short*)&v1;
#pragma unroll
          for (int r=0; r<4; ++r) AH1[fragAddr(k, qd*4 + r)] = sw[r];
        }
      }
    }
    __syncthreads();  // B3
  }

  // ---- final out accumulation (device-scope RMW, m20-verified) ----
  const float bos = bo[0];
  for (int i = tid; i < TT*16; i += 256){
    int t = i >> 4, row = i & 15;
    float v = outLDS[t][row];
    if (c == 0) v += bos;
    atomicAdd(&out[(rowbase + row)*TT + t], v);
  }
  sinkbuf[blockIdx.x] = sink;  // consume exch results (prevents downgrade)
}

// ---------------- launch ----------------
extern "C" void kernel_launch(void* const* d_in, const int* in_sizes, int n_in,
                              void* d_out, int out_size, void* d_ws, size_t ws_size,
                              hipStream_t stream)
{
  const float* x    = (const float*)d_in[0];
  const float* xs   = (const float*)d_in[1];
  const float* Wih0 = (const float*)d_in[2];
  const float* Whh0 = (const float*)d_in[3];
  const float* bih0 = (const float*)d_in[4];
  const float* bhh0 = (const float*)d_in[5];
  const float* Wih1 = (const float*)d_in[6];
  const float* Whh1 = (const float*)d_in[7];
  const float* bih1 = (const float*)d_in[8];
  const float* bhh1 = (const float*)d_in[9];
  const float* Ws   = (const float*)d_in[10];
  const float* bs   = (const float*)d_in[11];
  const float* Wo   = (const float*)d_in[12];
  const float* bo   = (const float*)d_in[13];
  float* out = (float*)d_out;

  char* ws = (char*)d_ws;
  short*    Wb0   = (short*)(ws);                // 589824
  short*    Wb1   = (short*)(ws + 589824);       // 1048576 -> 1638400
  float*    h0i   = (float*)(ws + 1638400);      // 524288  -> 2162688
  float*    b0cp  = (float*)(ws + 2162688);      // 4096    -> 2166784
  float*    b1cp  = (float*)(ws + 2166784);      // 4096    -> 2170880
  short*    ring0 = (short*)(ws + 2170880);      // 1048576 -> 3219456
  short*    ring1 = (short*)(ws + 3219456);      // 1048576 -> 4268032
  unsigned* flags = (unsigned*)(ws + 4268032);   // 16384   -> 4284416
  unsigned* sinkb = (unsigned*)(ws + 4284416);   // 512     -> ~4.28 MB total

  int nswz = 16*36*512 + 16*64*512;
  hipLaunchKernelGGL(prep_weights, dim3((nswz+255)/256), dim3(256), 0, stream,
                     Wih0, Whh0, Wih1, Whh1, Wb0, Wb1);
  hipLaunchKernelGGL(prep_h0, dim3(512), dim3(256), 0, stream, xs, Ws, bs, h0i);
  hipLaunchKernelGGL(prep_bias, dim3(8), dim3(256), 0, stream, bih0, bhh0, bih1, bhh1, b0cp, b1cp);
  hipLaunchKernelGGL(prep_zero, dim3((BB*TT+255)/256), dim3(256), 0, stream, out, flags);

  hipLaunchKernelGGL(lstm_fused, dim3(128), dim3(256), 0, stream,
                     Wb0, Wb1, h0i, b0cp, b1cp, x, Wo, bo,
                     ring0, ring1, flags, sinkb, out);
}